// Round 1
// baseline (1464.516 us; speedup 1.0000x reference)
//
#include <hip/hip_runtime.h>
#include <cstdint>

#define HEADS 4
#define GBATCH 64

// ---------------- generic fp32 tiled GEMM with fused epilogue ----------------
// C[M,NC] = op( A[M,K] @ B[K,NC] + bias[NC] - sub[batch[row], NC] )
template<int BM, int BN, int TM, int TN>
__global__ __launch_bounds__(256)
void gemm_f32(const float* __restrict__ A, const float* __restrict__ B,
              const float* __restrict__ bias, const float* __restrict__ sub,
              const int* __restrict__ batch, float* __restrict__ C,
              int M, int K, int NC, int do_relu)
{
    constexpr int BK = 64;
    constexpr int PAD = 4;
    __shared__ float As[BM][BK + PAD];
    __shared__ float Bs[BK][BN + PAD];
    const int tid = threadIdx.x;
    const int tx = tid & 15;   // 16 thread-cols
    const int ty = tid >> 4;   // 16 thread-rows
    const int row0 = blockIdx.x * BM;
    const int col0 = blockIdx.y * BN;

    float acc[TM][TN];
#pragma unroll
    for (int i = 0; i < TM; ++i)
#pragma unroll
        for (int j = 0; j < TN; ++j) acc[i][j] = 0.f;

    for (int k0 = 0; k0 < K; k0 += BK) {
        // stage A tile (BM x BK), float4 along K
#pragma unroll
        for (int t = tid; t < BM * (BK / 4); t += 256) {
            int r = t >> 4;             // BK/4 == 16
            int c4 = (t & 15) << 2;
            int gr = row0 + r;
            float4 v = make_float4(0.f, 0.f, 0.f, 0.f);
            if (gr < M) v = *(const float4*)&A[(size_t)gr * K + k0 + c4];
            *(float4*)&As[r][c4] = v;
        }
        constexpr int BN4 = BN / 4;
        // stage B tile (BK x BN)
#pragma unroll
        for (int t = tid; t < BK * BN4; t += 256) {
            int r = t / BN4;
            int c4 = (t - r * BN4) << 2;
            float4 v = *(const float4*)&B[(size_t)(k0 + r) * NC + col0 + c4];
            *(float4*)&Bs[r][c4] = v;
        }
        __syncthreads();
#pragma unroll
        for (int kk = 0; kk < BK; kk += 4) {
            float4 a4[TM];
#pragma unroll
            for (int i = 0; i < TM; ++i)
                a4[i] = *(const float4*)&As[ty * TM + i][kk];
#pragma unroll
            for (int kq = 0; kq < 4; ++kq) {
                float4 b4[TN / 4];
#pragma unroll
                for (int j4 = 0; j4 < TN / 4; ++j4)
                    b4[j4] = *(const float4*)&Bs[kk + kq][tx * TN + j4 * 4];
#pragma unroll
                for (int i = 0; i < TM; ++i) {
                    float av = (kq == 0) ? a4[i].x : (kq == 1) ? a4[i].y
                             : (kq == 2) ? a4[i].z : a4[i].w;
#pragma unroll
                    for (int j4 = 0; j4 < TN / 4; ++j4) {
                        acc[i][j4 * 4 + 0] = fmaf(av, b4[j4].x, acc[i][j4 * 4 + 0]);
                        acc[i][j4 * 4 + 1] = fmaf(av, b4[j4].y, acc[i][j4 * 4 + 1]);
                        acc[i][j4 * 4 + 2] = fmaf(av, b4[j4].z, acc[i][j4 * 4 + 2]);
                        acc[i][j4 * 4 + 3] = fmaf(av, b4[j4].w, acc[i][j4 * 4 + 3]);
                    }
                }
            }
        }
        __syncthreads();
    }
    // epilogue
#pragma unroll
    for (int i = 0; i < TM; ++i) {
        int gr = row0 + ty * TM + i;
        if (gr >= M) continue;
        int bidx = (sub != nullptr) ? batch[gr] : 0;
#pragma unroll
        for (int j4 = 0; j4 < TN / 4; ++j4) {
            int gc = col0 + tx * TN + j4 * 4;
            float4 v;
            v.x = acc[i][j4 * 4 + 0]; v.y = acc[i][j4 * 4 + 1];
            v.z = acc[i][j4 * 4 + 2]; v.w = acc[i][j4 * 4 + 3];
            if (bias) {
                float4 bv = *(const float4*)&bias[gc];
                v.x += bv.x; v.y += bv.y; v.z += bv.z; v.w += bv.w;
            }
            if (sub) {
                float4 sv = *(const float4*)&sub[(size_t)bidx * NC + gc];
                v.x -= sv.x; v.y -= sv.y; v.z -= sv.z; v.w -= sv.w;
            }
            if (do_relu) {
                v.x = fmaxf(v.x, 0.f); v.y = fmaxf(v.y, 0.f);
                v.z = fmaxf(v.z, 0.f); v.w = fmaxf(v.w, 0.f);
            }
            *(float4*)&C[(size_t)gr * NC + gc] = v;
        }
    }
}

// ---------------- build per-head [W_h | W_h@A_h] and bias [b_h | b_h@A_h] ----
__global__ __launch_bounds__(128)
void assemble_att(const float* __restrict__ W_att, const float* __restrict__ b_att,
                  const float* __restrict__ A_att, float* __restrict__ Bcat,
                  float* __restrict__ biascat)
{
    int h = blockIdx.y;
    int i = blockIdx.x;   // k-row 0..127
    int j = threadIdx.x;  // 0..127
    const float* W  = W_att + (size_t)h * 128 * 128;
    const float* Aa = A_att + (size_t)h * 128 * 128;
    float* Bh = Bcat + (size_t)h * 128 * 256;
    Bh[(size_t)i * 256 + j] = W[i * 128 + j];
    float acc = 0.f;
    for (int k = 0; k < 128; ++k)
        acc = fmaf(W[i * 128 + k], Aa[k * 128 + j], acc);
    Bh[(size_t)i * 256 + 128 + j] = acc;
    if (i == 0) {
        biascat[h * 256 + j] = b_att[h * 128 + j];
        float bacc = 0.f;
        for (int k = 0; k < 128; ++k)
            bacc = fmaf(b_att[h * 128 + k], Aa[k * 128 + j], bacc);
        biascat[h * 256 + 128 + j] = bacc;
    }
}

// ------------- W_eff = W_f2 @ (W_l0[2j]+W_l0[2j+1]);  b_eff likewise ---------
__global__ __launch_bounds__(64)
void build_weff(const float* __restrict__ W_f2, const float* __restrict__ b_f2,
                const float* __restrict__ W_l0, const float* __restrict__ b_l0,
                float* __restrict__ Weff, float* __restrict__ beff)
{
    int o = threadIdx.x;  // 0..63
    int k = blockIdx.x;   // 0..256, block 256 builds bias
    if (k < 256) {
        float a = 0.f;
        for (int j = 0; j < 8; ++j) {
            float w = W_l0[(2 * j) * 64 + o] + W_l0[(2 * j + 1) * 64 + o];
            a = fmaf(W_f2[k * 8 + j], w, a);
        }
        Weff[k * 64 + o] = a;
    } else {
        float a = b_l0[o];
        for (int j = 0; j < 8; ++j) {
            float w = W_l0[(2 * j) * 64 + o] + W_l0[(2 * j + 1) * 64 + o];
            a = fmaf(b_f2[j], w, a);
        }
        beff[o] = a;
    }
}

// ---------------- per-edge bilinear score, accumulated over heads ------------
__global__ __launch_bounds__(256)
void edge_score(const float* __restrict__ tmp, const int* __restrict__ row,
                const int* __restrict__ col, float* __restrict__ acc,
                float* __restrict__ att_out, int E, int head)
{
    int e = (int)((blockIdx.x * blockDim.x + threadIdx.x) >> 6);
    int lane = threadIdx.x & 63;
    if (e >= E) return;
    int r = row[e];
    int c = col[e];
    float2 y2 = *(const float2*)&tmp[(size_t)r * 256 + 128 + lane * 2];
    float2 h2 = *(const float2*)&tmp[(size_t)c * 256 + lane * 2];
    float p = y2.x * h2.x + y2.y * h2.y;
#pragma unroll
    for (int m = 32; m > 0; m >>= 1) p += __shfl_xor(p, m, 64);
    if (lane == 0) {
        float s = p + (head == 0 ? 0.f : acc[e]);
        if (head == HEADS - 1) {
            s *= 0.25f;
            att_out[e] = 1.f / (1.f + expf(-s));
        } else {
            acc[e] = s;
        }
    }
}

// -------- segment sums over sorted batch (64 features), run-length + atomics -
__global__ __launch_bounds__(256)
void segmean_accum(const float* __restrict__ v, const int* __restrict__ batch,
                   float* __restrict__ sums, float* __restrict__ cnt,
                   int N, int do_cnt)
{
    const int lane = threadIdx.x & 63;
    const int w = threadIdx.x >> 6;
    int start = (blockIdx.x * 4 + w) * 64;
    if (start >= N) return;
    int end = min(start + 64, N);
    int cur = batch[start];
    float acc = 0.f;
    float run = 0.f;
    for (int i = start; i < end; ++i) {
        int g = batch[i];
        if (g != cur) {
            atomicAdd(&sums[cur * 64 + lane], acc);
            if (do_cnt && lane == 0) atomicAdd(&cnt[cur], run);
            cur = g; acc = 0.f; run = 0.f;
        }
        acc += v[(size_t)i * 64 + lane];
        run += 1.f;
    }
    atomicAdd(&sums[cur * 64 + lane], acc);
    if (do_cnt && lane == 0) atomicAdd(&cnt[cur], run);
}

// ---------------- xm = (sums/cnt) @ L  (G x Fout) ----------------------------
__global__ void xm_compute(const float* __restrict__ sums, const float* __restrict__ cnt,
                           const float* __restrict__ L, float* __restrict__ xm, int Fout)
{
    int g = blockIdx.x;
    int j = threadIdx.x;
    float inv = 1.f / fmaxf(cnt[g], 1.f);
    float a = 0.f;
    for (int k = 0; k < 64; ++k)
        a = fmaf(sums[g * 64 + k] * inv, L[k * Fout + j], a);
    xm[g * Fout + j] = a;
}

// ---------------- BN column sums over relu(x0f) ------------------------------
__global__ __launch_bounds__(256)
void bn_stats(const float* __restrict__ x0f, float* __restrict__ bnsum,
              float* __restrict__ bnsumsq, int N)
{
    const int f = threadIdx.x & 127;
    const int q = threadIdx.x >> 7;
    int i0 = blockIdx.x * 512 + q;
    int iend = min(blockIdx.x * 512 + 512, N);
    float s = 0.f, ss = 0.f;
    for (int i = i0; i < iend; i += 2) {
        float v = fmaxf(x0f[(size_t)i * 128 + f], 0.f);
        s += v;
        ss = fmaf(v, v, ss);
    }
    atomicAdd(&bnsum[f], s);
    atomicAdd(&bnsumsq[f], ss);
}

__global__ __launch_bounds__(128)
void bn_final(const float* __restrict__ bnsum, const float* __restrict__ bnsumsq,
              const float* __restrict__ gamma, const float* __restrict__ beta,
              float* __restrict__ scale, float* __restrict__ shift, float invN)
{
    int f = threadIdx.x;
    float mu = bnsum[f] * invN;
    float var = bnsumsq[f] * invN - mu * mu;
    float sc = gamma[f] * rsqrtf(var + 1e-5f);
    scale[f] = sc;
    shift[f] = beta[f] - mu * sc;
}

// ---------------- out = x + relu(x0f)*scale + shift --------------------------
__global__ __launch_bounds__(256)
void finalize(const float* __restrict__ x, const float* __restrict__ x0f,
              const float* __restrict__ scale, const float* __restrict__ shift,
              float* __restrict__ out, int total4)
{
    int i = blockIdx.x * blockDim.x + threadIdx.x;
    if (i >= total4) return;
    int f0 = (i * 4) & 127;
    float4 h = ((const float4*)x0f)[i];
    float4 xv = ((const float4*)x)[i];
    float4 sc = *(const float4*)&scale[f0];
    float4 sh = *(const float4*)&shift[f0];
    float4 o;
    o.x = xv.x + fmaxf(h.x, 0.f) * sc.x + sh.x;
    o.y = xv.y + fmaxf(h.y, 0.f) * sc.y + sh.y;
    o.z = xv.z + fmaxf(h.z, 0.f) * sc.z + sh.z;
    o.w = xv.w + fmaxf(h.w, 0.f) * sc.w + sh.w;
    ((float4*)out)[i] = o;
}

extern "C" void kernel_launch(void* const* d_in, const int* in_sizes, int n_in,
                              void* d_out, int out_size, void* d_ws, size_t ws_size,
                              hipStream_t stream)
{
    const float* x      = (const float*)d_in[0];
    const int*   ei     = (const int*)d_in[1];
    const int*   batch  = (const int*)d_in[2];
    const float* W_f1   = (const float*)d_in[3];
    const float* b_f1   = (const float*)d_in[4];
    const float* W_f2   = (const float*)d_in[5];
    const float* b_f2   = (const float*)d_in[6];
    const float* W_l0   = (const float*)d_in[7];
    const float* b_l0   = (const float*)d_in[8];
    const float* G1     = (const float*)d_in[9];
    const float* b_g1   = (const float*)d_in[10];
    const float* L1     = (const float*)d_in[11];
    const float* G2     = (const float*)d_in[12];
    const float* b_g2   = (const float*)d_in[13];
    const float* L2     = (const float*)d_in[14];
    const float* gam    = (const float*)d_in[15];
    const float* bet    = (const float*)d_in[16];
    const float* W_att  = (const float*)d_in[17];
    const float* b_att  = (const float*)d_in[18];
    const float* A_att  = (const float*)d_in[19];

    const int N = in_sizes[2];        // nodes
    const int E = in_sizes[1] / 2;    // edges

    float* ws = (float*)d_ws;
    size_t o = 0;
    float* Bcat    = ws + o; o += (size_t)HEADS * 128 * 256;
    float* biascat = ws + o; o += HEADS * 256;
    float* Weff    = ws + o; o += 256 * 64;
    float* beff    = ws + o; o += 64;
    float* attacc  = ws + o; o += (size_t)E;
    o = (o + 3) & ~(size_t)3;
    float* zreg    = ws + o;
    float* sums1   = ws + o; o += 64 * 64;
    float* sums2   = ws + o; o += 64 * 64;
    float* cnt     = ws + o; o += 64;
    float* bnsum   = ws + o; o += 128;
    float* bnsumsq = ws + o; o += 128;
    size_t zlen    = (ws + o) - zreg;
    float* xm1     = ws + o; o += 64 * 64;
    float* xm2     = ws + o; o += 64 * 128;
    float* bscale  = ws + o; o += 128;
    float* bshift  = ws + o; o += 128;
    float* headtmp = ws + o; o += (size_t)N * 256;   // per-head hx|y, then 'hidden'
    float* s0      = ws + o; o += (size_t)N * 64;
    float* s1b     = ws + o; o += (size_t)N * 64;
    float* x0f     = ws + o; o += (size_t)N * 128;

    if (ws_size < o * sizeof(float)) return;  // fail loudly (validation) rather than corrupt

    float* out0    = (float*)d_out;
    float* att_out = out0 + (size_t)N * 128;

    hipMemsetAsync(zreg, 0, zlen * sizeof(float), stream);
    assemble_att<<<dim3(128, 4), 128, 0, stream>>>(W_att, b_att, A_att, Bcat, biascat);
    build_weff<<<257, 64, 0, stream>>>(W_f2, b_f2, W_l0, b_l0, Weff, beff);

    const int gm128 = (N + 127) / 128;
    const int gm64  = (N + 63) / 64;

    // attention, one head at a time (reuses headtmp)
    for (int h = 0; h < HEADS; ++h) {
        gemm_f32<128, 128, 8, 8><<<dim3(gm128, 2), 256, 0, stream>>>(
            x, Bcat + (size_t)h * 128 * 256, biascat + h * 256, nullptr, nullptr,
            headtmp, N, 128, 256, 0);
        edge_score<<<(E + 3) / 4, 256, 0, stream>>>(headtmp, ei, ei + E,
                                                    attacc, att_out, E, h);
    }

    // hidden = relu(x @ W_f1 + b_f1)
    gemm_f32<128, 128, 8, 8><<<dim3(gm128, 2), 256, 0, stream>>>(
        x, W_f1, b_f1, nullptr, nullptr, headtmp, N, 128, 256, 1);
    // s0 = relu(hidden @ W_eff + b_eff)
    gemm_f32<64, 64, 4, 4><<<dim3(gm64, 1), 256, 0, stream>>>(
        headtmp, Weff, beff, nullptr, nullptr, s0, N, 256, 64, 1);
    segmean_accum<<<(N + 255) / 256, 256, 0, stream>>>(s0, batch, sums1, cnt, N, 1);
    xm_compute<<<64, 64, 0, stream>>>(sums1, cnt, L1, xm1, 64);
    // s1 = relu(s0 @ G1 + b_g1 - xm1[batch])
    gemm_f32<64, 64, 4, 4><<<dim3(gm64, 1), 256, 0, stream>>>(
        s0, G1, b_g1, xm1, batch, s1b, N, 64, 64, 1);
    segmean_accum<<<(N + 255) / 256, 256, 0, stream>>>(s1b, batch, sums2, cnt, N, 0);
    xm_compute<<<64, 128, 0, stream>>>(sums2, cnt, L2, xm2, 128);
    // x0f = s1 @ G2 + b_g2 - xm2[batch]
    gemm_f32<128, 128, 8, 8><<<dim3(gm128, 1), 256, 0, stream>>>(
        s1b, G2, b_g2, xm2, batch, x0f, N, 64, 128, 0);

    bn_stats<<<(N + 511) / 512, 256, 0, stream>>>(x0f, bnsum, bnsumsq, N);
    bn_final<<<1, 128, 0, stream>>>(bnsum, bnsumsq, gam, bet, bscale, bshift, 1.f / (float)N);
    finalize<<<((N * 128 / 4) + 255) / 256, 256, 0, stream>>>(x, x0f, bscale, bshift,
                                                              out0, N * 128 / 4);
}

// Round 2
// 817.556 us; speedup vs baseline: 1.7913x; 1.7913x over previous
//
#include <hip/hip_runtime.h>
#include <cstdint>

#define HEADS 4

typedef __attribute__((ext_vector_type(8))) short bf16x8;
typedef __attribute__((ext_vector_type(4))) float floatx4;

__device__ __forceinline__ short f2bf(float f) {
    union { float f; unsigned u; } v; v.f = f;
    unsigned r = v.u + 0x7FFFu + ((v.u >> 16) & 1u);
    return (short)(r >> 16);
}
__device__ __forceinline__ float bflo(unsigned u) {
    union { unsigned u; float f; } v; v.u = u << 16; return v.f;
}
__device__ __forceinline__ float bfhi(unsigned u) {
    union { unsigned u; float f; } v; v.u = u & 0xffff0000u; return v.f;
}
__device__ __forceinline__ void async16(const void* g, void* l) {
    __builtin_amdgcn_global_load_lds((const __attribute__((address_space(1))) void*)g,
                                     (__attribute__((address_space(3))) void*)l,
                                     16, 0, 0);
}

// ================= bf16 MFMA GEMM (m97-style) ================================
// A: [Mpad][K] bf16 row-major (K mult of 32), Bt: [NC][K] bf16 (i.e. B^T),
// C = A @ B + bias, optional relu; fp32 and/or bf16 outputs.
// Block: 256 thr = 4 waves, tile 128 x BN, BK=32.
template<int BN>
__global__ __launch_bounds__(256)
void gemm_mfma(const short* __restrict__ A, const short* __restrict__ Bt,
               const float* __restrict__ bias,
               float* __restrict__ Cf, short* __restrict__ Cb,
               int M, int K, int NC, int do_relu)
{
    constexpr int WC  = BN / 64;          // wave cols (2 for BN=128, 1 for BN=64)
    constexpr int NWR = 4 / WC;           // wave rows
    constexpr int MI  = 128 / (16 * NWR); // 16x16 m-tiles per wave (4 or 2)
    __shared__ short Asm[128 * 32];
    __shared__ short Bsm[BN * 32];

    const int tid  = threadIdx.x;
    const int lane = tid & 63;
    const int wv   = tid >> 6;
    const int wc   = wv % WC;
    const int wr   = wv / WC;
    const int row0 = blockIdx.x * 128;
    const int col0 = blockIdx.y * BN;
    const int lq   = lane >> 4;           // quad 0..3
    const int lr   = lane & 15;
    const int sw   = lq ^ ((lr >> 1) & 3);  // swizzled chunk for frag reads

    floatx4 acc[MI][4];
#pragma unroll
    for (int mi = 0; mi < MI; ++mi)
#pragma unroll
        for (int ni = 0; ni < 4; ++ni) acc[mi][ni] = (floatx4)(0.f);

    const short* gA = A + (size_t)row0 * K;
    const short* gB = Bt + (size_t)col0 * K;

    for (int k0 = 0; k0 < K; k0 += 32) {
        __syncthreads();
        // stage A tile: 128 rows x 4 chunks(16B); chunk (row,c) <- global chunk c^((row>>1)&3)
#pragma unroll
        for (int p = 0; p < 2; ++p) {
            int cidb = p * 256 + wv * 64;             // wave-uniform chunk base
            int cid  = cidb + lane;
            int row  = cid >> 2, c = cid & 3;
            int cg   = c ^ ((row >> 1) & 3);
            async16(gA + (size_t)row * K + k0 + cg * 8, &Asm[cidb * 8]);
        }
#pragma unroll
        for (int p = 0; p < WC; ++p) {
            int cidb = p * 256 + wv * 64;
            int cid  = cidb + lane;
            int row  = cid >> 2, c = cid & 3;
            int cg   = c ^ ((row >> 1) & 3);
            async16(gB + (size_t)row * K + k0 + cg * 8, &Bsm[cidb * 8]);
        }
        __syncthreads();

        bf16x8 af[MI], bfr[4];
#pragma unroll
        for (int mi = 0; mi < MI; ++mi)
            af[mi] = *(const bf16x8*)&Asm[(wr * 16 * MI + mi * 16 + lr) * 32 + sw * 8];
#pragma unroll
        for (int ni = 0; ni < 4; ++ni)
            bfr[ni] = *(const bf16x8*)&Bsm[(wc * 64 + ni * 16 + lr) * 32 + sw * 8];
#pragma unroll
        for (int mi = 0; mi < MI; ++mi)
#pragma unroll
            for (int ni = 0; ni < 4; ++ni)
                acc[mi][ni] = __builtin_amdgcn_mfma_f32_16x16x32_bf16(
                    af[mi], bfr[ni], acc[mi][ni], 0, 0, 0);
    }

    // epilogue: C/D layout col=lane&15, row=quad*4+reg
#pragma unroll
    for (int ni = 0; ni < 4; ++ni) {
        int gc = col0 + wc * 64 + ni * 16 + lr;
        float bv = bias ? bias[gc] : 0.f;
#pragma unroll
        for (int mi = 0; mi < MI; ++mi) {
            int gr0 = row0 + wr * 16 * MI + mi * 16 + lq * 4;
#pragma unroll
            for (int r = 0; r < 4; ++r) {
                int gr = gr0 + r;
                if (gr >= M) continue;
                float v = acc[mi][ni][r] + bv;
                if (do_relu) v = fmaxf(v, 0.f);
                if (Cf) Cf[(size_t)gr * NC + gc] = v;
                if (Cb) Cb[(size_t)gr * NC + gc] = f2bf(v);
            }
        }
    }
}

// ---------------- generic fp32 tiled GEMM with fused epilogue ----------------
template<int BM, int BN, int TM, int TN>
__global__ __launch_bounds__(256)
void gemm_f32(const float* __restrict__ A, const float* __restrict__ B,
              const float* __restrict__ bias, const float* __restrict__ sub,
              const int* __restrict__ batch, float* __restrict__ C,
              int M, int K, int NC, int do_relu)
{
    constexpr int BK = 64;
    constexpr int PAD = 4;
    __shared__ float As[BM][BK + PAD];
    __shared__ float Bs[BK][BN + PAD];
    const int tid = threadIdx.x;
    const int tx = tid & 15;
    const int ty = tid >> 4;
    const int row0 = blockIdx.x * BM;
    const int col0 = blockIdx.y * BN;

    float acc[TM][TN];
#pragma unroll
    for (int i = 0; i < TM; ++i)
#pragma unroll
        for (int j = 0; j < TN; ++j) acc[i][j] = 0.f;

    for (int k0 = 0; k0 < K; k0 += BK) {
#pragma unroll
        for (int t = tid; t < BM * (BK / 4); t += 256) {
            int r = t >> 4;
            int c4 = (t & 15) << 2;
            int gr = row0 + r;
            float4 v = make_float4(0.f, 0.f, 0.f, 0.f);
            if (gr < M) v = *(const float4*)&A[(size_t)gr * K + k0 + c4];
            *(float4*)&As[r][c4] = v;
        }
        constexpr int BN4 = BN / 4;
#pragma unroll
        for (int t = tid; t < BK * BN4; t += 256) {
            int r = t / BN4;
            int c4 = (t - r * BN4) << 2;
            float4 v = *(const float4*)&B[(size_t)(k0 + r) * NC + col0 + c4];
            *(float4*)&Bs[r][c4] = v;
        }
        __syncthreads();
#pragma unroll
        for (int kk = 0; kk < BK; kk += 4) {
            float4 a4[TM];
#pragma unroll
            for (int i = 0; i < TM; ++i)
                a4[i] = *(const float4*)&As[ty * TM + i][kk];
#pragma unroll
            for (int kq = 0; kq < 4; ++kq) {
                float4 b4[TN / 4];
#pragma unroll
                for (int j4 = 0; j4 < TN / 4; ++j4)
                    b4[j4] = *(const float4*)&Bs[kk + kq][tx * TN + j4 * 4];
#pragma unroll
                for (int i = 0; i < TM; ++i) {
                    float av = (kq == 0) ? a4[i].x : (kq == 1) ? a4[i].y
                             : (kq == 2) ? a4[i].z : a4[i].w;
#pragma unroll
                    for (int j4 = 0; j4 < TN / 4; ++j4) {
                        acc[i][j4 * 4 + 0] = fmaf(av, b4[j4].x, acc[i][j4 * 4 + 0]);
                        acc[i][j4 * 4 + 1] = fmaf(av, b4[j4].y, acc[i][j4 * 4 + 1]);
                        acc[i][j4 * 4 + 2] = fmaf(av, b4[j4].z, acc[i][j4 * 4 + 2]);
                        acc[i][j4 * 4 + 3] = fmaf(av, b4[j4].w, acc[i][j4 * 4 + 3]);
                    }
                }
            }
        }
        __syncthreads();
    }
#pragma unroll
    for (int i = 0; i < TM; ++i) {
        int gr = row0 + ty * TM + i;
        if (gr >= M) continue;
        int bidx = (sub != nullptr) ? batch[gr] : 0;
#pragma unroll
        for (int j4 = 0; j4 < TN / 4; ++j4) {
            int gc = col0 + tx * TN + j4 * 4;
            float4 v;
            v.x = acc[i][j4 * 4 + 0]; v.y = acc[i][j4 * 4 + 1];
            v.z = acc[i][j4 * 4 + 2]; v.w = acc[i][j4 * 4 + 3];
            if (bias) {
                float4 bv = *(const float4*)&bias[gc];
                v.x += bv.x; v.y += bv.y; v.z += bv.z; v.w += bv.w;
            }
            if (sub) {
                float4 sv = *(const float4*)&sub[(size_t)bidx * NC + gc];
                v.x -= sv.x; v.y -= sv.y; v.z -= sv.z; v.w -= sv.w;
            }
            if (do_relu) {
                v.x = fmaxf(v.x, 0.f); v.y = fmaxf(v.y, 0.f);
                v.z = fmaxf(v.z, 0.f); v.w = fmaxf(v.w, 0.f);
            }
            *(float4*)&C[(size_t)gr * NC + gc] = v;
        }
    }
}

// ---------------- x fp32 -> bf16 (padded with zeros) -------------------------
__global__ __launch_bounds__(256)
void f32_to_bf16_pad(const float* __restrict__ in, short* __restrict__ out,
                     long n_in, long n_out)
{
    long i4 = ((long)blockIdx.x * 256 + threadIdx.x) * 4;
    if (i4 >= n_out) return;
    float4 v = make_float4(0.f, 0.f, 0.f, 0.f);
    if (i4 < n_in) v = *(const float4*)&in[i4];
    short4 o;
    o.x = f2bf(v.x); o.y = f2bf(v.y); o.z = f2bf(v.z); o.w = f2bf(v.w);
    *(short4*)&out[i4] = o;
}

// ------- per-head B^T = [W_h | W_h@A_h]^T (bf16) and bias [b_h | b_h@A_h] ----
__global__ __launch_bounds__(128)
void assemble_att(const float* __restrict__ W_att, const float* __restrict__ b_att,
                  const float* __restrict__ A_att, short* __restrict__ Bcat_t,
                  float* __restrict__ biascat)
{
    int h = blockIdx.y;
    int i = blockIdx.x;   // k 0..127
    int j = threadIdx.x;  // n 0..127
    const float* W  = W_att + (size_t)h * 128 * 128;
    const float* Aa = A_att + (size_t)h * 128 * 128;
    short* Bh = Bcat_t + (size_t)h * 256 * 128;
    Bh[(size_t)j * 128 + i] = f2bf(W[i * 128 + j]);
    float acc = 0.f;
    for (int k = 0; k < 128; ++k)
        acc = fmaf(W[i * 128 + k], Aa[k * 128 + j], acc);
    Bh[(size_t)(128 + j) * 128 + i] = f2bf(acc);
    if (i == 0) {
        biascat[h * 256 + j] = b_att[h * 128 + j];
        float bacc = 0.f;
        for (int k = 0; k < 128; ++k)
            bacc = fmaf(b_att[h * 128 + k], Aa[k * 128 + j], bacc);
        biascat[h * 256 + 128 + j] = bacc;
    }
}

// --------- W_f1^T in bf16: Wt[c][r] = W_f1[r][c],  (128x256 -> 256x128) ------
__global__ __launch_bounds__(256)
void wf1_transpose(const float* __restrict__ W, short* __restrict__ Wt)
{
    int r = blockIdx.x;    // 0..127
    int c = threadIdx.x;   // 0..255
    Wt[(size_t)c * 128 + r] = f2bf(W[(size_t)r * 256 + c]);
}

// ---- Wefft[o][k] = (W_f2 @ (W_l0[2j]+W_l0[2j+1]))[k][o] bf16; beff fp32 -----
__global__ __launch_bounds__(64)
void build_weff(const float* __restrict__ W_f2, const float* __restrict__ b_f2,
                const float* __restrict__ W_l0, const float* __restrict__ b_l0,
                short* __restrict__ Wefft, float* __restrict__ beff)
{
    int o = threadIdx.x;  // 0..63
    int k = blockIdx.x;   // 0..256
    if (k < 256) {
        float a = 0.f;
        for (int j = 0; j < 8; ++j) {
            float w = W_l0[(2 * j) * 64 + o] + W_l0[(2 * j + 1) * 64 + o];
            a = fmaf(W_f2[k * 8 + j], w, a);
        }
        Wefft[(size_t)o * 256 + k] = f2bf(a);
    } else {
        float a = b_l0[o];
        for (int j = 0; j < 8; ++j) {
            float w = W_l0[(2 * j) * 64 + o] + W_l0[(2 * j + 1) * 64 + o];
            a = fmaf(b_f2[j], w, a);
        }
        beff[o] = a;
    }
}

// ---------------- per-edge bilinear score from bf16 hx|y ---------------------
__global__ __launch_bounds__(256)
void edge_score_bf16(const short* __restrict__ tmp, const int* __restrict__ row,
                     const int* __restrict__ col, float* __restrict__ acc,
                     float* __restrict__ att_out, int E, int head)
{
    int e = (int)((blockIdx.x * blockDim.x + threadIdx.x) >> 6);
    int lane = threadIdx.x & 63;
    if (e >= E) return;
    int r = row[e];
    int c = col[e];
    unsigned y2 = *(const unsigned*)&tmp[(size_t)r * 256 + 128 + lane * 2];
    unsigned h2 = *(const unsigned*)&tmp[(size_t)c * 256 + lane * 2];
    float p = bflo(y2) * bflo(h2) + bfhi(y2) * bfhi(h2);
#pragma unroll
    for (int m = 32; m > 0; m >>= 1) p += __shfl_xor(p, m, 64);
    if (lane == 0) {
        float s = p + (head == 0 ? 0.f : acc[e]);
        if (head == HEADS - 1) {
            s *= 0.25f;
            att_out[e] = 1.f / (1.f + expf(-s));
        } else {
            acc[e] = s;
        }
    }
}

// -------- segment sums over sorted batch (64 features) -----------------------
__global__ __launch_bounds__(256)
void segmean_accum(const float* __restrict__ v, const int* __restrict__ batch,
                   float* __restrict__ sums, float* __restrict__ cnt,
                   int N, int do_cnt)
{
    const int lane = threadIdx.x & 63;
    const int w = threadIdx.x >> 6;
    int start = (blockIdx.x * 4 + w) * 64;
    if (start >= N) return;
    int end = min(start + 64, N);
    int cur = batch[start];
    float acc = 0.f;
    float run = 0.f;
    for (int i = start; i < end; ++i) {
        int g = batch[i];
        if (g != cur) {
            atomicAdd(&sums[cur * 64 + lane], acc);
            if (do_cnt && lane == 0) atomicAdd(&cnt[cur], run);
            cur = g; acc = 0.f; run = 0.f;
        }
        acc += v[(size_t)i * 64 + lane];
        run += 1.f;
    }
    atomicAdd(&sums[cur * 64 + lane], acc);
    if (do_cnt && lane == 0) atomicAdd(&cnt[cur], run);
}

__global__ void xm_compute(const float* __restrict__ sums, const float* __restrict__ cnt,
                           const float* __restrict__ L, float* __restrict__ xm, int Fout)
{
    int g = blockIdx.x;
    int j = threadIdx.x;
    float inv = 1.f / fmaxf(cnt[g], 1.f);
    float a = 0.f;
    for (int k = 0; k < 64; ++k)
        a = fmaf(sums[g * 64 + k] * inv, L[k * Fout + j], a);
    xm[g * Fout + j] = a;
}

__global__ __launch_bounds__(256)
void bn_stats(const float* __restrict__ x0f, float* __restrict__ bnsum,
              float* __restrict__ bnsumsq, int N)
{
    const int f = threadIdx.x & 127;
    const int q = threadIdx.x >> 7;
    int i0 = blockIdx.x * 512 + q;
    int iend = min(blockIdx.x * 512 + 512, N);
    float s = 0.f, ss = 0.f;
    for (int i = i0; i < iend; i += 2) {
        float v = fmaxf(x0f[(size_t)i * 128 + f], 0.f);
        s += v;
        ss = fmaf(v, v, ss);
    }
    atomicAdd(&bnsum[f], s);
    atomicAdd(&bnsumsq[f], ss);
}

__global__ __launch_bounds__(128)
void bn_final(const float* __restrict__ bnsum, const float* __restrict__ bnsumsq,
              const float* __restrict__ gamma, const float* __restrict__ beta,
              float* __restrict__ scale, float* __restrict__ shift, float invN)
{
    int f = threadIdx.x;
    float mu = bnsum[f] * invN;
    float var = bnsumsq[f] * invN - mu * mu;
    float sc = gamma[f] * rsqrtf(var + 1e-5f);
    scale[f] = sc;
    shift[f] = beta[f] - mu * sc;
}

__global__ __launch_bounds__(256)
void finalize(const float* __restrict__ x, const float* __restrict__ x0f,
              const float* __restrict__ scale, const float* __restrict__ shift,
              float* __restrict__ out, int total4)
{
    int i = blockIdx.x * blockDim.x + threadIdx.x;
    if (i >= total4) return;
    int f0 = (i * 4) & 127;
    float4 h = ((const float4*)x0f)[i];
    float4 xv = ((const float4*)x)[i];
    float4 sc = *(const float4*)&scale[f0];
    float4 sh = *(const float4*)&shift[f0];
    float4 o;
    o.x = xv.x + fmaxf(h.x, 0.f) * sc.x + sh.x;
    o.y = xv.y + fmaxf(h.y, 0.f) * sc.y + sh.y;
    o.z = xv.z + fmaxf(h.z, 0.f) * sc.z + sh.z;
    o.w = xv.w + fmaxf(h.w, 0.f) * sc.w + sh.w;
    ((float4*)out)[i] = o;
}

extern "C" void kernel_launch(void* const* d_in, const int* in_sizes, int n_in,
                              void* d_out, int out_size, void* d_ws, size_t ws_size,
                              hipStream_t stream)
{
    const float* x      = (const float*)d_in[0];
    const int*   ei     = (const int*)d_in[1];
    const int*   batch  = (const int*)d_in[2];
    const float* W_f1   = (const float*)d_in[3];
    const float* b_f1   = (const float*)d_in[4];
    const float* W_f2   = (const float*)d_in[5];
    const float* b_f2   = (const float*)d_in[6];
    const float* W_l0   = (const float*)d_in[7];
    const float* b_l0   = (const float*)d_in[8];
    const float* G1     = (const float*)d_in[9];
    const float* b_g1   = (const float*)d_in[10];
    const float* L1     = (const float*)d_in[11];
    const float* G2     = (const float*)d_in[12];
    const float* b_g2   = (const float*)d_in[13];
    const float* L2     = (const float*)d_in[14];
    const float* gam    = (const float*)d_in[15];
    const float* bet    = (const float*)d_in[16];
    const float* W_att  = (const float*)d_in[17];
    const float* b_att  = (const float*)d_in[18];
    const float* A_att  = (const float*)d_in[19];

    const int N = in_sizes[2];
    const int E = in_sizes[1] / 2;
    const int Npad = (N + 127) & ~127;

    char* p = (char*)d_ws;
    auto alloc = [&](size_t bytes) {
        char* r = p;
        p += (bytes + 255) & ~(size_t)255;
        return r;
    };

    short* x_bf    = (short*)alloc((size_t)Npad * 128 * 2);
    short* hid_bf  = (short*)alloc((size_t)Npad * 256 * 2);   // later overlaid by s1b
    short* head_bf = (short*)alloc((size_t)Npad * 256 * 2);   // later overlaid by x0f
    float* s0      = (float*)alloc((size_t)N * 64 * 4);
    float* attacc  = (float*)alloc((size_t)E * 4);
    short* Bcat_t  = (short*)alloc((size_t)HEADS * 256 * 128 * 2);
    float* biascat = (float*)alloc(HEADS * 256 * 4);
    short* Wf1t    = (short*)alloc(256 * 128 * 2);
    short* Wefft   = (short*)alloc(64 * 256 * 2);
    float* beff    = (float*)alloc(64 * 4);
    float* zblk    = (float*)alloc((64 * 64 + 64 * 64 + 64 + 128 + 128) * 4);
    float* xm1     = (float*)alloc(64 * 64 * 4);
    float* xm2     = (float*)alloc(64 * 128 * 4);
    float* bscale  = (float*)alloc(128 * 4);
    float* bshift  = (float*)alloc(128 * 4);

    if ((size_t)(p - (char*)d_ws) > ws_size) return;

    float* sums1   = zblk;
    float* sums2   = zblk + 64 * 64;
    float* cnt     = zblk + 64 * 64 * 2;
    float* bnsum   = cnt + 64;
    float* bnsumsq = bnsum + 128;
    // overlays (lifetimes disjoint on the stream's serial order):
    float* s1b = (float*)hid_bf;    // N*64*4  <= Npad*256*2
    float* x0f = (float*)head_bf;   // N*128*4 <= Npad*256*2

    float* out0    = (float*)d_out;
    float* att_out = out0 + (size_t)N * 128;

    hipMemsetAsync(zblk, 0, (64 * 64 * 2 + 64 + 256) * 4, stream);

    // prologue packing
    {
        long n_in_e = (long)N * 128, n_out_e = (long)Npad * 128;
        long blocks = (n_out_e / 4 + 255) / 256;
        f32_to_bf16_pad<<<(int)blocks, 256, 0, stream>>>(x, x_bf, n_in_e, n_out_e);
    }
    assemble_att<<<dim3(128, 4), 128, 0, stream>>>(W_att, b_att, A_att, Bcat_t, biascat);
    wf1_transpose<<<128, 256, 0, stream>>>(W_f1, Wf1t);
    build_weff<<<257, 64, 0, stream>>>(W_f2, b_f2, W_l0, b_l0, Wefft, beff);

    const int gmm = Npad / 128;
    const int gm64  = (N + 63) / 64;
    const int gm128 = (N + 127) / 128;

    // attention heads: hx|y = x @ [W|WA] (bf16 out), then edge bilinear scores
    for (int h = 0; h < HEADS; ++h) {
        gemm_mfma<128><<<dim3(gmm, 2), 256, 0, stream>>>(
            x_bf, Bcat_t + (size_t)h * 256 * 128, biascat + h * 256,
            nullptr, head_bf, N, 128, 256, 0);
        edge_score_bf16<<<(E + 3) / 4, 256, 0, stream>>>(head_bf, ei, ei + E,
                                                         attacc, att_out, E, h);
    }

    // hidden = relu(x @ W_f1 + b_f1)  (bf16 out)
    gemm_mfma<128><<<dim3(gmm, 2), 256, 0, stream>>>(
        x_bf, Wf1t, b_f1, nullptr, hid_bf, N, 128, 256, 1);
    // s0 = relu(hidden @ W_eff + b_eff)  (fp32 out)
    gemm_mfma<64><<<dim3(gmm, 1), 256, 0, stream>>>(
        hid_bf, Wefft, beff, s0, nullptr, N, 256, 64, 1);

    segmean_accum<<<(N + 255) / 256, 256, 0, stream>>>(s0, batch, sums1, cnt, N, 1);
    xm_compute<<<64, 64, 0, stream>>>(sums1, cnt, L1, xm1, 64);
    gemm_f32<64, 64, 4, 4><<<dim3(gm64, 1), 256, 0, stream>>>(
        s0, G1, b_g1, xm1, batch, s1b, N, 64, 64, 1);
    segmean_accum<<<(N + 255) / 256, 256, 0, stream>>>(s1b, batch, sums2, cnt, N, 0);
    xm_compute<<<64, 128, 0, stream>>>(sums2, cnt, L2, xm2, 128);
    gemm_f32<128, 128, 8, 8><<<dim3(gm128, 1), 256, 0, stream>>>(
        s1b, G2, b_g2, xm2, batch, x0f, N, 64, 128, 0);

    bn_stats<<<(N + 511) / 512, 256, 0, stream>>>(x0f, bnsum, bnsumsq, N);
    bn_final<<<1, 128, 0, stream>>>(bnsum, bnsumsq, gam, bet, bscale, bshift, 1.f / (float)N);
    finalize<<<((N * 128 / 4) + 255) / 256, 256, 0, stream>>>(x, x0f, bscale, bshift,
                                                              out0, N * 128 / 4);
}

// Round 3
// 613.859 us; speedup vs baseline: 2.3858x; 1.3318x over previous
//
#include <hip/hip_runtime.h>
#include <cstdint>

#define HEADS 4

typedef __attribute__((ext_vector_type(8))) short bf16x8;
typedef __attribute__((ext_vector_type(4))) float floatx4;

__device__ __forceinline__ short f2bf(float f) {
    union { float f; unsigned u; } v; v.f = f;
    unsigned r = v.u + 0x7FFFu + ((v.u >> 16) & 1u);
    return (short)(r >> 16);
}
__device__ __forceinline__ float bflo(unsigned u) {
    union { unsigned u; float f; } v; v.u = u << 16; return v.f;
}
__device__ __forceinline__ float bfhi(unsigned u) {
    union { unsigned u; float f; } v; v.u = u & 0xffff0000u; return v.f;
}
__device__ __forceinline__ float dot2(unsigned a, unsigned b) {
    return bflo(a) * bflo(b) + bfhi(a) * bfhi(b);
}
__device__ __forceinline__ void async16(const void* g, void* l) {
    __builtin_amdgcn_global_load_lds((const __attribute__((address_space(1))) void*)g,
                                     (__attribute__((address_space(3))) void*)l,
                                     16, 0, 0);
}

// ================= bf16 MFMA GEMM =================
// A: [Mpad][K] bf16 row-major (K mult of 32), Bt: [NC][K] bf16 (B^T).
// C = relu?( A@B + bias - sub[batch[row]] ); outputs fp32 (Cf) and/or bf16 (Cb).
// Optional fused BN column stats over relu(C): bnsum/bnsumsq atomics.
// Block: 256 thr = 4 waves, tile 128 x BN, BK=32.
template<int BN>
__global__ __launch_bounds__(256)
void gemm_mfma(const short* __restrict__ A, const short* __restrict__ Bt,
               const float* __restrict__ bias, const float* __restrict__ sub,
               const int* __restrict__ batch,
               float* __restrict__ Cf, short* __restrict__ Cb,
               float* __restrict__ bnsum, float* __restrict__ bnsumsq,
               int M, int K, int NC, int do_relu)
{
    constexpr int WC  = BN / 64;          // wave cols
    constexpr int NWR = 4 / WC;           // wave rows
    constexpr int MI  = 128 / (16 * NWR); // 16x16 m-tiles per wave
    __shared__ short Asm[128 * 32];
    __shared__ short Bsm[BN * 32];

    const int tid  = threadIdx.x;
    const int lane = tid & 63;
    const int wv   = tid >> 6;
    const int wc   = wv % WC;
    const int wr   = wv / WC;
    const int row0 = blockIdx.x * 128;
    const int col0 = blockIdx.y * BN;
    const int lq   = lane >> 4;
    const int lr   = lane & 15;
    const int sw   = lq ^ ((lr >> 1) & 3);

    floatx4 acc[MI][4];
#pragma unroll
    for (int mi = 0; mi < MI; ++mi)
#pragma unroll
        for (int ni = 0; ni < 4; ++ni) acc[mi][ni] = (floatx4)(0.f);

    const short* gA = A + (size_t)row0 * K;
    const short* gB = Bt + (size_t)col0 * K;

    for (int k0 = 0; k0 < K; k0 += 32) {
        __syncthreads();
#pragma unroll
        for (int p = 0; p < 2; ++p) {
            int cidb = p * 256 + wv * 64;
            int cid  = cidb + lane;
            int row  = cid >> 2, c = cid & 3;
            int cg   = c ^ ((row >> 1) & 3);
            async16(gA + (size_t)row * K + k0 + cg * 8, &Asm[cidb * 8]);
        }
#pragma unroll
        for (int p = 0; p < WC; ++p) {
            int cidb = p * 256 + wv * 64;
            int cid  = cidb + lane;
            int row  = cid >> 2, c = cid & 3;
            int cg   = c ^ ((row >> 1) & 3);
            async16(gB + (size_t)row * K + k0 + cg * 8, &Bsm[cidb * 8]);
        }
        __syncthreads();

        bf16x8 af[MI], bfr[4];
#pragma unroll
        for (int mi = 0; mi < MI; ++mi)
            af[mi] = *(const bf16x8*)&Asm[(wr * 16 * MI + mi * 16 + lr) * 32 + sw * 8];
#pragma unroll
        for (int ni = 0; ni < 4; ++ni)
            bfr[ni] = *(const bf16x8*)&Bsm[(wc * 64 + ni * 16 + lr) * 32 + sw * 8];
#pragma unroll
        for (int mi = 0; mi < MI; ++mi)
#pragma unroll
            for (int ni = 0; ni < 4; ++ni)
                acc[mi][ni] = __builtin_amdgcn_mfma_f32_16x16x32_bf16(
                    af[mi], bfr[ni], acc[mi][ni], 0, 0, 0);
    }

    // epilogue: C/D layout col=lane&15, row=quad*4+reg
    float bias_v[4];
#pragma unroll
    for (int ni = 0; ni < 4; ++ni) {
        int gc = col0 + wc * 64 + ni * 16 + lr;
        bias_v[ni] = bias ? bias[gc] : 0.f;
    }
    float s_acc[4] = {0.f, 0.f, 0.f, 0.f};
    float ss_acc[4] = {0.f, 0.f, 0.f, 0.f};

#pragma unroll
    for (int mi = 0; mi < MI; ++mi) {
#pragma unroll
        for (int r = 0; r < 4; ++r) {
            int gr = row0 + wr * 16 * MI + mi * 16 + lq * 4 + r;
            if (gr >= M) continue;
            int bidx = sub ? batch[gr] : 0;
#pragma unroll
            for (int ni = 0; ni < 4; ++ni) {
                int gc = col0 + wc * 64 + ni * 16 + lr;
                float v = acc[mi][ni][r] + bias_v[ni];
                if (sub) v -= sub[(size_t)bidx * NC + gc];
                if (do_relu) v = fmaxf(v, 0.f);
                if (Cf) Cf[(size_t)gr * NC + gc] = v;
                if (Cb) Cb[(size_t)gr * NC + gc] = f2bf(v);
                if (bnsum) {
                    float rv = fmaxf(v, 0.f);
                    s_acc[ni] += rv;
                    ss_acc[ni] = fmaf(rv, rv, ss_acc[ni]);
                }
            }
        }
    }
    if (bnsum) {
#pragma unroll
        for (int ni = 0; ni < 4; ++ni) {
            float sv = s_acc[ni], ssv = ss_acc[ni];
            sv += __shfl_xor(sv, 16); sv += __shfl_xor(sv, 32);
            ssv += __shfl_xor(ssv, 16); ssv += __shfl_xor(ssv, 32);
            if (lq == 0) {
                int gc = col0 + wc * 64 + ni * 16 + lr;
                atomicAdd(&bnsum[gc], sv);
                atomicAdd(&bnsumsq[gc], ssv);
            }
        }
    }
}

// ---------------- x fp32 -> bf16 (padded with zeros) -------------------------
__global__ __launch_bounds__(256)
void f32_to_bf16_pad(const float* __restrict__ in, short* __restrict__ out,
                     long n_in, long n_out)
{
    long i4 = ((long)blockIdx.x * 256 + threadIdx.x) * 4;
    if (i4 >= n_out) return;
    float4 v = make_float4(0.f, 0.f, 0.f, 0.f);
    if (i4 < n_in) v = *(const float4*)&in[i4];
    short4 o;
    o.x = f2bf(v.x); o.y = f2bf(v.y); o.z = f2bf(v.z); o.w = f2bf(v.w);
    *(short4*)&out[i4] = o;
}

// ------- per-head B^T = [W_h | W_h@A_h]^T (bf16) and bias [b_h | b_h@A_h] ----
__global__ __launch_bounds__(128)
void assemble_att(const float* __restrict__ W_att, const float* __restrict__ b_att,
                  const float* __restrict__ A_att, short* __restrict__ Bcat_t,
                  float* __restrict__ biascat)
{
    int h = blockIdx.y;
    int i = blockIdx.x;   // k 0..127
    int j = threadIdx.x;  // n 0..127
    const float* W  = W_att + (size_t)h * 128 * 128;
    const float* Aa = A_att + (size_t)h * 128 * 128;
    short* Bh = Bcat_t + (size_t)h * 256 * 128;
    Bh[(size_t)j * 128 + i] = f2bf(W[i * 128 + j]);
    float acc = 0.f;
    for (int k = 0; k < 128; ++k)
        acc = fmaf(W[i * 128 + k], Aa[k * 128 + j], acc);
    Bh[(size_t)(128 + j) * 128 + i] = f2bf(acc);
    if (i == 0) {
        biascat[h * 256 + j] = b_att[h * 128 + j];
        float bacc = 0.f;
        for (int k = 0; k < 128; ++k)
            bacc = fmaf(b_att[h * 128 + k], Aa[k * 128 + j], bacc);
        biascat[h * 256 + 128 + j] = bacc;
    }
}

// --------- W_f1^T in bf16 (128x256 -> 256x128) -------------------------------
__global__ __launch_bounds__(256)
void wf1_transpose(const float* __restrict__ W, short* __restrict__ Wt)
{
    int r = blockIdx.x;    // 0..127
    int c = threadIdx.x;   // 0..255
    Wt[(size_t)c * 128 + r] = f2bf(W[(size_t)r * 256 + c]);
}

// --------- G1 (64x64) -> G1t[64][64] bf16; G2 (64x128) -> G2t[128][64] bf16 --
__global__ __launch_bounds__(64)
void transpose_g(const float* __restrict__ G1, const float* __restrict__ G2,
                 short* __restrict__ G1t, short* __restrict__ G2t)
{
    int b = blockIdx.x;
    int j = threadIdx.x;  // 0..63
    if (b < 64) {
        // b = k, j = n
        G1t[(size_t)j * 64 + b] = f2bf(G1[(size_t)b * 64 + j]);
    } else {
        int n = b - 64;   // 0..127, j = k
        G2t[(size_t)n * 64 + j] = f2bf(G2[(size_t)j * 128 + n]);
    }
}

// ---- Wefft[o][k] = (W_f2 @ (W_l0[2j]+W_l0[2j+1]))[k][o] bf16; beff fp32 -----
__global__ __launch_bounds__(64)
void build_weff(const float* __restrict__ W_f2, const float* __restrict__ b_f2,
                const float* __restrict__ W_l0, const float* __restrict__ b_l0,
                short* __restrict__ Wefft, float* __restrict__ beff)
{
    int o = threadIdx.x;  // 0..63
    int k = blockIdx.x;   // 0..256
    if (k < 256) {
        float a = 0.f;
        for (int j = 0; j < 8; ++j) {
            float w = W_l0[(2 * j) * 64 + o] + W_l0[(2 * j + 1) * 64 + o];
            a = fmaf(W_f2[k * 8 + j], w, a);
        }
        Wefft[(size_t)o * 256 + k] = f2bf(a);
    } else {
        float a = b_l0[o];
        for (int j = 0; j < 8; ++j) {
            float w = W_l0[(2 * j) * 64 + o] + W_l0[(2 * j + 1) * 64 + o];
            a = fmaf(b_f2[j], w, a);
        }
        beff[o] = a;
    }
}

// ------------- per-edge bilinear score: 16 lanes per edge, uint4 loads -------
__global__ __launch_bounds__(256)
void edge_score_bf16(const short* __restrict__ tmp, const int* __restrict__ row,
                     const int* __restrict__ col, float* __restrict__ acc,
                     float* __restrict__ att_out, int E, int head)
{
    int t = blockIdx.x * 256 + threadIdx.x;
    int e = t >> 4;
    int j = t & 15;
    if (e >= E) return;
    int r = row[e];
    int c = col[e];
    uint4 ya = *(const uint4*)&tmp[(size_t)r * 256 + 128 + j * 8];
    uint4 ha = *(const uint4*)&tmp[(size_t)c * 256 + j * 8];
    float p = dot2(ya.x, ha.x) + dot2(ya.y, ha.y) + dot2(ya.z, ha.z) + dot2(ya.w, ha.w);
    p += __shfl_xor(p, 1);
    p += __shfl_xor(p, 2);
    p += __shfl_xor(p, 4);
    p += __shfl_xor(p, 8);
    if (j == 0) {
        float s = p + (head == 0 ? 0.f : acc[e]);
        if (head == HEADS - 1) {
            s *= 0.25f;
            att_out[e] = 1.f / (1.f + expf(-s));
        } else {
            acc[e] = s;
        }
    }
}

// -------- segment sums over sorted batch (64 features), float4 per lane ------
__global__ __launch_bounds__(256)
void segmean_accum(const float* __restrict__ v, const int* __restrict__ batch,
                   float* __restrict__ sums, float* __restrict__ cnt,
                   int N, int do_cnt)
{
    const int lane = threadIdx.x & 63;
    const int wv = threadIdx.x >> 6;
    const int lq = lane >> 4;   // row phase 0..3
    const int lr = lane & 15;   // col quad
    int start = (blockIdx.x * 4 + wv) * 64;
    if (start >= N) return;
    int end = min(start + 64, N);
    int i = start + lq;
    float4 a = make_float4(0.f, 0.f, 0.f, 0.f);
    float run = 0.f;
    int cur = (i < end) ? batch[i] : -1;
    for (; i < end; i += 4) {
        int g = batch[i];
        if (g != cur) {
            float* s = &sums[(size_t)cur * 64 + lr * 4];
            atomicAdd(&s[0], a.x); atomicAdd(&s[1], a.y);
            atomicAdd(&s[2], a.z); atomicAdd(&s[3], a.w);
            if (do_cnt && lr == 0) atomicAdd(&cnt[cur], run);
            cur = g; a = make_float4(0.f, 0.f, 0.f, 0.f); run = 0.f;
        }
        float4 vv = *(const float4*)&v[(size_t)i * 64 + lr * 4];
        a.x += vv.x; a.y += vv.y; a.z += vv.z; a.w += vv.w;
        run += 1.f;
    }
    if (cur >= 0) {
        float* s = &sums[(size_t)cur * 64 + lr * 4];
        atomicAdd(&s[0], a.x); atomicAdd(&s[1], a.y);
        atomicAdd(&s[2], a.z); atomicAdd(&s[3], a.w);
        if (do_cnt && lr == 0) atomicAdd(&cnt[cur], run);
    }
}

__global__ void xm_compute(const float* __restrict__ sums, const float* __restrict__ cnt,
                           const float* __restrict__ L, float* __restrict__ xm, int Fout)
{
    int g = blockIdx.x;
    int j = threadIdx.x;
    float inv = 1.f / fmaxf(cnt[g], 1.f);
    float a = 0.f;
    for (int k = 0; k < 64; ++k)
        a = fmaf(sums[g * 64 + k] * inv, L[k * Fout + j], a);
    xm[g * Fout + j] = a;
}

__global__ __launch_bounds__(128)
void bn_final(const float* __restrict__ bnsum, const float* __restrict__ bnsumsq,
              const float* __restrict__ gamma, const float* __restrict__ beta,
              float* __restrict__ scale, float* __restrict__ shift, float invN)
{
    int f = threadIdx.x;
    float mu = bnsum[f] * invN;
    float var = bnsumsq[f] * invN - mu * mu;
    float sc = gamma[f] * rsqrtf(var + 1e-5f);
    scale[f] = sc;
    shift[f] = beta[f] - mu * sc;
}

__global__ __launch_bounds__(256)
void finalize(const float* __restrict__ x, const float* __restrict__ x0f,
              const float* __restrict__ scale, const float* __restrict__ shift,
              float* __restrict__ out, int total4)
{
    int i = blockIdx.x * blockDim.x + threadIdx.x;
    if (i >= total4) return;
    int f0 = (i * 4) & 127;
    float4 h = ((const float4*)x0f)[i];
    float4 xv = ((const float4*)x)[i];
    float4 sc = *(const float4*)&scale[f0];
    float4 sh = *(const float4*)&shift[f0];
    float4 o;
    o.x = xv.x + fmaxf(h.x, 0.f) * sc.x + sh.x;
    o.y = xv.y + fmaxf(h.y, 0.f) * sc.y + sh.y;
    o.z = xv.z + fmaxf(h.z, 0.f) * sc.z + sh.z;
    o.w = xv.w + fmaxf(h.w, 0.f) * sc.w + sh.w;
    ((float4*)out)[i] = o;
}

extern "C" void kernel_launch(void* const* d_in, const int* in_sizes, int n_in,
                              void* d_out, int out_size, void* d_ws, size_t ws_size,
                              hipStream_t stream)
{
    const float* x      = (const float*)d_in[0];
    const int*   ei     = (const int*)d_in[1];
    const int*   batch  = (const int*)d_in[2];
    const float* W_f1   = (const float*)d_in[3];
    const float* b_f1   = (const float*)d_in[4];
    const float* W_f2   = (const float*)d_in[5];
    const float* b_f2   = (const float*)d_in[6];
    const float* W_l0   = (const float*)d_in[7];
    const float* b_l0   = (const float*)d_in[8];
    const float* G1     = (const float*)d_in[9];
    const float* b_g1   = (const float*)d_in[10];
    const float* L1     = (const float*)d_in[11];
    const float* G2     = (const float*)d_in[12];
    const float* b_g2   = (const float*)d_in[13];
    const float* L2     = (const float*)d_in[14];
    const float* gam    = (const float*)d_in[15];
    const float* bet    = (const float*)d_in[16];
    const float* W_att  = (const float*)d_in[17];
    const float* b_att  = (const float*)d_in[18];
    const float* A_att  = (const float*)d_in[19];

    const int N = in_sizes[2];
    const int E = in_sizes[1] / 2;
    const int Npad = (N + 127) & ~127;

    char* p = (char*)d_ws;
    auto alloc = [&](size_t bytes) {
        char* r = p;
        p += (bytes + 255) & ~(size_t)255;
        return r;
    };

    short* x_bf    = (short*)alloc((size_t)Npad * 128 * 2);
    char*  regionA = alloc((size_t)Npad * 256 * 2);   // hidden bf16 -> s1b fp32 + s1_bf
    char*  regionB = alloc((size_t)Npad * 256 * 2);   // head_bf -> s0_bf -> x0f fp32
    float* s0      = (float*)alloc((size_t)N * 64 * 4);
    float* attacc  = (float*)alloc((size_t)E * 4);
    short* Bcat_t  = (short*)alloc((size_t)HEADS * 256 * 128 * 2);
    float* biascat = (float*)alloc(HEADS * 256 * 4);
    short* Wf1t    = (short*)alloc(256 * 128 * 2);
    short* Wefft   = (short*)alloc(64 * 256 * 2);
    float* beff    = (float*)alloc(64 * 4);
    short* G1t     = (short*)alloc(64 * 64 * 2);
    short* G2t     = (short*)alloc(128 * 64 * 2);
    float* zblk    = (float*)alloc((64 * 64 * 2 + 64 + 256) * 4);
    float* xm1     = (float*)alloc(64 * 64 * 4);
    float* xm2     = (float*)alloc(64 * 128 * 4);
    float* bscale  = (float*)alloc(128 * 4);
    float* bshift  = (float*)alloc(128 * 4);

    if ((size_t)(p - (char*)d_ws) > ws_size) return;

    float* sums1   = zblk;
    float* sums2   = zblk + 64 * 64;
    float* cnt     = zblk + 64 * 64 * 2;
    float* bnsum   = cnt + 64;
    float* bnsumsq = bnsum + 128;

    // overlays (lifetimes disjoint in stream order)
    short* hid_bf  = (short*)regionA;                              // filtration out, dead after s0 gemm
    float* s1b     = (float*)regionA;                              // N*64*4
    short* s1_bf   = (short*)(regionA + (((size_t)N * 64 * 4 + 255) & ~(size_t)255)); // Npad*64*2
    short* head_bf = (short*)regionB;                              // per-head hx|y, dead after edge h3
    short* s0_bf   = (short*)regionB;                              // Npad*64*2, dead after G1
    float* x0f     = (float*)regionB;                              // N*128*4 (written by G2)

    float* out0    = (float*)d_out;
    float* att_out = out0 + (size_t)N * 128;

    hipMemsetAsync(zblk, 0, (64 * 64 * 2 + 64 + 256) * 4, stream);

    // prologue packing
    {
        long n_in_e = (long)N * 128, n_out_e = (long)Npad * 128;
        long blocks = (n_out_e / 4 + 255) / 256;
        f32_to_bf16_pad<<<(int)blocks, 256, 0, stream>>>(x, x_bf, n_in_e, n_out_e);
    }
    assemble_att<<<dim3(128, 4), 128, 0, stream>>>(W_att, b_att, A_att, Bcat_t, biascat);
    wf1_transpose<<<128, 256, 0, stream>>>(W_f1, Wf1t);
    build_weff<<<257, 64, 0, stream>>>(W_f2, b_f2, W_l0, b_l0, Wefft, beff);
    transpose_g<<<192, 64, 0, stream>>>(G1, G2, G1t, G2t);

    const int gmm = Npad / 128;

    // attention heads
    for (int h = 0; h < HEADS; ++h) {
        gemm_mfma<128><<<dim3(gmm, 2), 256, 0, stream>>>(
            x_bf, Bcat_t + (size_t)h * 256 * 128, biascat + h * 256,
            nullptr, nullptr, nullptr, head_bf, nullptr, nullptr, N, 128, 256, 0);
        edge_score_bf16<<<(E * 16 + 255) / 256, 256, 0, stream>>>(
            head_bf, ei, ei + E, attacc, att_out, E, h);
    }

    // hidden = relu(x @ W_f1 + b_f1)  (bf16)
    gemm_mfma<128><<<dim3(gmm, 2), 256, 0, stream>>>(
        x_bf, Wf1t, b_f1, nullptr, nullptr, nullptr, hid_bf, nullptr, nullptr,
        N, 128, 256, 1);
    // s0 = relu(hidden @ W_eff + b_eff)  (fp32 + bf16)
    gemm_mfma<64><<<dim3(gmm, 1), 256, 0, stream>>>(
        hid_bf, Wefft, beff, nullptr, nullptr, s0, s0_bf, nullptr, nullptr,
        N, 256, 64, 1);

    segmean_accum<<<(N + 255) / 256, 256, 0, stream>>>(s0, batch, sums1, cnt, N, 1);
    xm_compute<<<64, 64, 0, stream>>>(sums1, cnt, L1, xm1, 64);
    // s1 = relu(s0 @ G1 + b_g1 - xm1[batch])  (fp32 + bf16)
    gemm_mfma<64><<<dim3(gmm, 1), 256, 0, stream>>>(
        s0_bf, G1t, b_g1, xm1, batch, s1b, s1_bf, nullptr, nullptr,
        N, 64, 64, 1);
    segmean_accum<<<(N + 255) / 256, 256, 0, stream>>>(s1b, batch, sums2, cnt, N, 0);
    xm_compute<<<64, 128, 0, stream>>>(sums2, cnt, L2, xm2, 128);
    // x0f = s1 @ G2 + b_g2 - xm2[batch]  (fp32) + fused BN column stats
    gemm_mfma<128><<<dim3(gmm, 1), 256, 0, stream>>>(
        s1_bf, G2t, b_g2, xm2, batch, x0f, nullptr, bnsum, bnsumsq,
        N, 64, 128, 0);

    bn_final<<<1, 128, 0, stream>>>(bnsum, bnsumsq, gam, bet, bscale, bshift, 1.f / (float)N);
    finalize<<<((N * 128 / 4) + 255) / 256, 256, 0, stream>>>(x, x0f, bscale, bshift,
                                                              out0, N * 128 / 4);
}

// Round 4
// 478.602 us; speedup vs baseline: 3.0600x; 1.2826x over previous
//
#include <hip/hip_runtime.h>
#include <cstdint>

#define HEADS 4

typedef __attribute__((ext_vector_type(8))) short bf16x8;
typedef __attribute__((ext_vector_type(4))) float floatx4;

__device__ __forceinline__ short f2bf(float f) {
    union { float f; unsigned u; } v; v.f = f;
    unsigned r = v.u + 0x7FFFu + ((v.u >> 16) & 1u);
    return (short)(r >> 16);
}
__device__ __forceinline__ float bflo(unsigned u) {
    union { unsigned u; float f; } v; v.u = u << 16; return v.f;
}
__device__ __forceinline__ float bfhi(unsigned u) {
    union { unsigned u; float f; } v; v.u = u & 0xffff0000u; return v.f;
}
__device__ __forceinline__ float dot2(unsigned a, unsigned b) {
    return bflo(a) * bflo(b) + bfhi(a) * bfhi(b);
}
__device__ __forceinline__ void async16(const void* g, void* l) {
    __builtin_amdgcn_global_load_lds((const __attribute__((address_space(1))) void*)g,
                                     (__attribute__((address_space(3))) void*)l,
                                     16, 0, 0);
}

// ================= bf16 MFMA GEMM, bf16 output via LDS-coalesced epilogue ====
// A: [Npad][K] bf16 (K mult of 32), Bt: [NC][K] bf16 (B^T).
// Cb = relu?( A@B + bias - sub[batch[row]] ) in bf16.
// Optional fused BN column stats over relu(C) for rows < M.
// Block: 256 thr = 4 waves, tile 128 x BN, BK=32. Rows up to Npad are written
// (buffers are Npad-sized); batch[] reads and BN stats are masked to < M.
template<int BN>
__global__ __launch_bounds__(256)
void gemm_mfma(const short* __restrict__ A, const short* __restrict__ Bt,
               const float* __restrict__ bias, const float* __restrict__ sub,
               const int* __restrict__ batch, short* __restrict__ Cb,
               float* __restrict__ bnsum, float* __restrict__ bnsumsq,
               int M, int K, int NC, int do_relu)
{
    constexpr int WC  = BN / 64;          // wave cols
    constexpr int NWR = 4 / WC;           // wave rows
    constexpr int MI  = 128 / (16 * NWR); // 16x16 m-tiles per wave
    constexpr int BNP = BN + 8;           // padded LDS stride for epilogue
    __shared__ short smem[128 * 32 + BN * 32];
    short* Asm = smem;
    short* Bsm = smem + 128 * 32;

    const int tid  = threadIdx.x;
    const int lane = tid & 63;
    const int wv   = tid >> 6;
    const int wc   = wv % WC;
    const int wr   = wv / WC;
    const int row0 = blockIdx.x * 128;
    const int col0 = blockIdx.y * BN;
    const int lq   = lane >> 4;
    const int lr   = lane & 15;
    const int sw   = lq ^ ((lr >> 1) & 3);

    floatx4 acc[MI][4];
#pragma unroll
    for (int mi = 0; mi < MI; ++mi)
#pragma unroll
        for (int ni = 0; ni < 4; ++ni) acc[mi][ni] = (floatx4)(0.f);

    const short* gA = A + (size_t)row0 * K;
    const short* gB = Bt + (size_t)col0 * K;

    for (int k0 = 0; k0 < K; k0 += 32) {
        __syncthreads();
#pragma unroll
        for (int p = 0; p < 2; ++p) {
            int cidb = p * 256 + wv * 64;
            int cid  = cidb + lane;
            int row  = cid >> 2, c = cid & 3;
            int cg   = c ^ ((row >> 1) & 3);
            async16(gA + (size_t)row * K + k0 + cg * 8, &Asm[cidb * 8]);
        }
#pragma unroll
        for (int p = 0; p < WC; ++p) {
            int cidb = p * 256 + wv * 64;
            int cid  = cidb + lane;
            int row  = cid >> 2, c = cid & 3;
            int cg   = c ^ ((row >> 1) & 3);
            async16(gB + (size_t)row * K + k0 + cg * 8, &Bsm[cidb * 8]);
        }
        __syncthreads();

        bf16x8 af[MI], bfr[4];
#pragma unroll
        for (int mi = 0; mi < MI; ++mi)
            af[mi] = *(const bf16x8*)&Asm[(wr * 16 * MI + mi * 16 + lr) * 32 + sw * 8];
#pragma unroll
        for (int ni = 0; ni < 4; ++ni)
            bfr[ni] = *(const bf16x8*)&Bsm[(wc * 64 + ni * 16 + lr) * 32 + sw * 8];
#pragma unroll
        for (int mi = 0; mi < MI; ++mi)
#pragma unroll
            for (int ni = 0; ni < 4; ++ni)
                acc[mi][ni] = __builtin_amdgcn_mfma_f32_16x16x32_bf16(
                    af[mi], bfr[ni], acc[mi][ni], 0, 0, 0);
    }

    // ---- epilogue: regs -> LDS slice (bf16) -> coalesced dwordx4 stores ----
    short* Csm = smem;  // reuse (guarded by barriers)
    float bias_v[4];
#pragma unroll
    for (int ni = 0; ni < 4; ++ni)
        bias_v[ni] = bias ? bias[col0 + wc * 64 + ni * 16 + lr] : 0.f;
    float s_acc[4] = {0.f, 0.f, 0.f, 0.f};
    float ss_acc[4] = {0.f, 0.f, 0.f, 0.f};

#pragma unroll
    for (int mi = 0; mi < MI; ++mi) {
        __syncthreads();
#pragma unroll
        for (int r = 0; r < 4; ++r) {
            int gr = row0 + wr * 16 * MI + mi * 16 + lq * 4 + r;
            int bidx = sub ? batch[min(gr, M - 1)] : 0;
#pragma unroll
            for (int ni = 0; ni < 4; ++ni) {
                int sc = wc * 64 + ni * 16 + lr;
                float v = acc[mi][ni][r] + bias_v[ni];
                if (sub) v -= sub[(size_t)bidx * NC + col0 + sc];
                if (do_relu) v = fmaxf(v, 0.f);
                if (bnsum && gr < M) {
                    float rv = fmaxf(v, 0.f);
                    s_acc[ni] += rv;
                    ss_acc[ni] = fmaf(rv, rv, ss_acc[ni]);
                }
                Csm[(wr * 16 + lq * 4 + r) * BNP + sc] = f2bf(v);
            }
        }
        __syncthreads();
        // read back coalesced: 256 threads, each one 16-short chunk
        int lrow = tid / (BN / 16);
        int chk  = tid % (BN / 16);
        int wrg  = lrow >> 4, r16 = lrow & 15;
        int gr   = row0 + wrg * 16 * MI + mi * 16 + r16;
        uint4 d0 = *(const uint4*)&Csm[lrow * BNP + chk * 16];
        uint4 d1 = *(const uint4*)&Csm[lrow * BNP + chk * 16 + 8];
        *(uint4*)&Cb[(size_t)gr * NC + col0 + chk * 16] = d0;
        *(uint4*)&Cb[(size_t)gr * NC + col0 + chk * 16 + 8] = d1;
    }

    if (bnsum) {
#pragma unroll
        for (int ni = 0; ni < 4; ++ni) {
            float sv = s_acc[ni], ssv = ss_acc[ni];
            sv += __shfl_xor(sv, 16); sv += __shfl_xor(sv, 32);
            ssv += __shfl_xor(ssv, 16); ssv += __shfl_xor(ssv, 32);
            if (lq == 0) {
                int gc = col0 + wc * 64 + ni * 16 + lr;
                atomicAdd(&bnsum[gc], sv);
                atomicAdd(&bnsumsq[gc], ssv);
            }
        }
    }
}

// ---------------- x fp32 -> bf16 (padded with zeros) -------------------------
__global__ __launch_bounds__(256)
void f32_to_bf16_pad(const float* __restrict__ in, short* __restrict__ out,
                     long n_in, long n_out)
{
    long i4 = ((long)blockIdx.x * 256 + threadIdx.x) * 4;
    if (i4 >= n_out) return;
    float4 v = make_float4(0.f, 0.f, 0.f, 0.f);
    if (i4 < n_in) v = *(const float4*)&in[i4];
    short4 o;
    o.x = f2bf(v.x); o.y = f2bf(v.y); o.z = f2bf(v.z); o.w = f2bf(v.w);
    *(short4*)&out[i4] = o;
}

// ---- attention fold: T[h] = A_h @ W_h^T -------------------------------------
__global__ __launch_bounds__(128)
void att_fold1(const float* __restrict__ A_att, const float* __restrict__ W_att,
               float* __restrict__ T)
{
    int h = blockIdx.y, i = blockIdx.x, j = threadIdx.x;
    const float* A = A_att + (size_t)h * 16384;
    const float* W = W_att + (size_t)h * 16384;
    float s = 0.f;
    for (int k = 0; k < 128; ++k) s = fmaf(A[i * 128 + k], W[j * 128 + k], s);
    T[(size_t)h * 16384 + i * 128 + j] = s;
}

// ---- M = sum_h W_h @ T_h ; stored transposed bf16: Mt[n][k] = M[k][n] -------
__global__ __launch_bounds__(128)
void att_fold2(const float* __restrict__ W_att, const float* __restrict__ T,
               short* __restrict__ Mt)
{
    int i = blockIdx.x, j = threadIdx.x;
    float s = 0.f;
    for (int h = 0; h < HEADS; ++h) {
        const float* W = W_att + (size_t)h * 16384 + i * 128;
        const float* Th = T + (size_t)h * 16384;
        for (int k = 0; k < 128; ++k) s = fmaf(W[k], Th[k * 128 + j], s);
    }
    Mt[(size_t)j * 128 + i] = f2bf(s);
}

// ---- u = sum W_h(A_h b_h), v = sum (b_h A_h)W_h^T, c0 = sum b_h.(A_h b_h) ---
__global__ __launch_bounds__(128)
void att_fold3(const float* __restrict__ W_att, const float* __restrict__ b_att,
               const float* __restrict__ A_att,
               float* __restrict__ u, float* __restrict__ v, float* __restrict__ c0)
{
    __shared__ float tb[HEADS][128], tv[HEADS][128];
    int t = threadIdx.x;
    for (int h = 0; h < HEADS; ++h) {
        const float* A = A_att + (size_t)h * 16384;
        const float* b = b_att + h * 128;
        float sb = 0.f, sv = 0.f;
        for (int j = 0; j < 128; ++j) {
            sb = fmaf(A[t * 128 + j], b[j], sb);
            sv = fmaf(b[j], A[j * 128 + t], sv);
        }
        tb[h][t] = sb; tv[h][t] = sv;
    }
    __syncthreads();
    float su = 0.f, sv2 = 0.f;
    for (int h = 0; h < HEADS; ++h) {
        const float* W = W_att + (size_t)h * 16384 + t * 128;
        for (int k = 0; k < 128; ++k) {
            su = fmaf(W[k], tb[h][k], su);
            sv2 = fmaf(W[k], tv[h][k], sv2);
        }
    }
    u[t] = su; v[t] = sv2;
    if (t == 0) {
        float c = 0.f;
        for (int h = 0; h < HEADS; ++h)
            for (int k = 0; k < 128; ++k) c += b_att[h * 128 + k] * tb[h][k];
        *c0 = c;
    }
}

// ---- per-node a = x.u, b = x.v ----------------------------------------------
__global__ __launch_bounds__(256)
void node_ab(const float* __restrict__ x, const float* __restrict__ u,
             const float* __restrict__ v, float* __restrict__ a,
             float* __restrict__ b, int N)
{
    int t = blockIdx.x * 256 + threadIdx.x;
    int n = t >> 4, j = t & 15;
    if (n >= N) return;
    const float* xr = x + (size_t)n * 128 + j * 8;
    float4 x0 = *(const float4*)xr;
    float4 x1 = *(const float4*)(xr + 4);
    const float* up = u + j * 8;
    const float* vp = v + j * 8;
    float sa = x0.x*up[0] + x0.y*up[1] + x0.z*up[2] + x0.w*up[3]
             + x1.x*up[4] + x1.y*up[5] + x1.z*up[6] + x1.w*up[7];
    float sb = x0.x*vp[0] + x0.y*vp[1] + x0.z*vp[2] + x0.w*vp[3]
             + x1.x*vp[4] + x1.y*vp[5] + x1.z*vp[6] + x1.w*vp[7];
    sa += __shfl_xor(sa, 1); sa += __shfl_xor(sa, 2);
    sa += __shfl_xor(sa, 4); sa += __shfl_xor(sa, 8);
    sb += __shfl_xor(sb, 1); sb += __shfl_xor(sb, 2);
    sb += __shfl_xor(sb, 4); sb += __shfl_xor(sb, 8);
    if (j == 0) { a[n] = sa; b[n] = sb; }
}

// ---- edge attention: sigmoid(0.25*(q[r].x[c] + a[r] + b[c] + c0)) ----------
__global__ __launch_bounds__(256)
void edge_att(const short* __restrict__ q, const short* __restrict__ xb,
              const int* __restrict__ row, const int* __restrict__ col,
              const float* __restrict__ a, const float* __restrict__ b,
              const float* __restrict__ c0, float* __restrict__ att, int E)
{
    int t = blockIdx.x * 256 + threadIdx.x;
    int e = t >> 4, j = t & 15;
    if (e >= E) return;
    int r = row[e], c = col[e];
    uint4 qa = *(const uint4*)&q[(size_t)r * 128 + j * 8];
    uint4 xa = *(const uint4*)&xb[(size_t)c * 128 + j * 8];
    float p = dot2(qa.x, xa.x) + dot2(qa.y, xa.y) + dot2(qa.z, xa.z) + dot2(qa.w, xa.w);
    p += __shfl_xor(p, 1); p += __shfl_xor(p, 2);
    p += __shfl_xor(p, 4); p += __shfl_xor(p, 8);
    if (j == 0) {
        float s = 0.25f * (p + a[r] + b[c] + *c0);
        att[e] = 1.f / (1.f + expf(-s));
    }
}

// --------- W_f1^T in bf16 (128x256 -> 256x128) -------------------------------
__global__ __launch_bounds__(256)
void wf1_transpose(const float* __restrict__ W, short* __restrict__ Wt)
{
    int r = blockIdx.x;    // 0..127
    int c = threadIdx.x;   // 0..255
    Wt[(size_t)c * 128 + r] = f2bf(W[(size_t)r * 256 + c]);
}

// --------- G1 (64x64) -> G1t bf16; G2 (64x128) -> G2t[128][64] bf16 ----------
__global__ __launch_bounds__(64)
void transpose_g(const float* __restrict__ G1, const float* __restrict__ G2,
                 short* __restrict__ G1t, short* __restrict__ G2t)
{
    int b = blockIdx.x;
    int j = threadIdx.x;
    if (b < 64) {
        G1t[(size_t)j * 64 + b] = f2bf(G1[(size_t)b * 64 + j]);
    } else {
        int n = b - 64;
        G2t[(size_t)n * 64 + j] = f2bf(G2[(size_t)j * 128 + n]);
    }
}

// ---- Wefft[o][k] = (W_f2 @ (W_l0[2j]+W_l0[2j+1]))[k][o] bf16; beff fp32 -----
__global__ __launch_bounds__(64)
void build_weff(const float* __restrict__ W_f2, const float* __restrict__ b_f2,
                const float* __restrict__ W_l0, const float* __restrict__ b_l0,
                short* __restrict__ Wefft, float* __restrict__ beff)
{
    int o = threadIdx.x;
    int k = blockIdx.x;
    if (k < 256) {
        float a = 0.f;
        for (int j = 0; j < 8; ++j) {
            float w = W_l0[(2 * j) * 64 + o] + W_l0[(2 * j + 1) * 64 + o];
            a = fmaf(W_f2[k * 8 + j], w, a);
        }
        Wefft[(size_t)o * 256 + k] = f2bf(a);
    } else {
        float a = b_l0[o];
        for (int j = 0; j < 8; ++j) {
            float w = W_l0[(2 * j) * 64 + o] + W_l0[(2 * j + 1) * 64 + o];
            a = fmaf(b_f2[j], w, a);
        }
        beff[o] = a;
    }
}

// -------- segment sums over sorted batch, 64 bf16 features -------------------
__global__ __launch_bounds__(256)
void segmean_bf(const short* __restrict__ v, const int* __restrict__ batch,
                float* __restrict__ sums, float* __restrict__ cnt,
                int N, int do_cnt)
{
    const int lane = threadIdx.x & 63;
    const int wv = threadIdx.x >> 6;
    const int lq = lane >> 4;
    const int lr = lane & 15;
    int start = (blockIdx.x * 4 + wv) * 64;
    if (start >= N) return;
    int end = min(start + 64, N);
    int i = start + lq;
    float4 a = make_float4(0.f, 0.f, 0.f, 0.f);
    float run = 0.f;
    int cur = (i < end) ? batch[i] : -1;
    for (; i < end; i += 4) {
        int g = batch[i];
        if (g != cur) {
            float* s = &sums[(size_t)cur * 64 + lr * 4];
            atomicAdd(&s[0], a.x); atomicAdd(&s[1], a.y);
            atomicAdd(&s[2], a.z); atomicAdd(&s[3], a.w);
            if (do_cnt && lr == 0) atomicAdd(&cnt[cur], run);
            cur = g; a = make_float4(0.f, 0.f, 0.f, 0.f); run = 0.f;
        }
        uint2 d = *(const uint2*)&v[(size_t)i * 64 + lr * 4];
        a.x += bflo(d.x); a.y += bfhi(d.x);
        a.z += bflo(d.y); a.w += bfhi(d.y);
        run += 1.f;
    }
    if (cur >= 0) {
        float* s = &sums[(size_t)cur * 64 + lr * 4];
        atomicAdd(&s[0], a.x); atomicAdd(&s[1], a.y);
        atomicAdd(&s[2], a.z); atomicAdd(&s[3], a.w);
        if (do_cnt && lr == 0) atomicAdd(&cnt[cur], run);
    }
}

__global__ void xm_compute(const float* __restrict__ sums, const float* __restrict__ cnt,
                           const float* __restrict__ L, float* __restrict__ xm, int Fout)
{
    int g = blockIdx.x;
    int j = threadIdx.x;
    float inv = 1.f / fmaxf(cnt[g], 1.f);
    float a = 0.f;
    for (int k = 0; k < 64; ++k)
        a = fmaf(sums[g * 64 + k] * inv, L[k * Fout + j], a);
    xm[g * Fout + j] = a;
}

__global__ __launch_bounds__(128)
void bn_final(const float* __restrict__ bnsum, const float* __restrict__ bnsumsq,
              const float* __restrict__ gamma, const float* __restrict__ beta,
              float* __restrict__ scale, float* __restrict__ shift, float invN)
{
    int f = threadIdx.x;
    float mu = bnsum[f] * invN;
    float var = bnsumsq[f] * invN - mu * mu;
    float sc = gamma[f] * rsqrtf(var + 1e-5f);
    scale[f] = sc;
    shift[f] = beta[f] - mu * sc;
}

// ---------------- out = x + relu(x0_bf)*scale + shift ------------------------
__global__ __launch_bounds__(256)
void finalize(const float* __restrict__ x, const short* __restrict__ x0b,
              const float* __restrict__ scale, const float* __restrict__ shift,
              float* __restrict__ out, int total4)
{
    int i = blockIdx.x * blockDim.x + threadIdx.x;
    if (i >= total4) return;
    int f0 = (i * 4) & 127;
    uint2 h2 = ((const uint2*)x0b)[i];
    float4 xv = ((const float4*)x)[i];
    float4 sc = *(const float4*)&scale[f0];
    float4 sh = *(const float4*)&shift[f0];
    float4 o;
    o.x = xv.x + fmaxf(bflo(h2.x), 0.f) * sc.x + sh.x;
    o.y = xv.y + fmaxf(bfhi(h2.x), 0.f) * sc.y + sh.y;
    o.z = xv.z + fmaxf(bflo(h2.y), 0.f) * sc.z + sh.z;
    o.w = xv.w + fmaxf(bfhi(h2.y), 0.f) * sc.w + sh.w;
    ((float4*)out)[i] = o;
}

extern "C" void kernel_launch(void* const* d_in, const int* in_sizes, int n_in,
                              void* d_out, int out_size, void* d_ws, size_t ws_size,
                              hipStream_t stream)
{
    const float* x      = (const float*)d_in[0];
    const int*   ei     = (const int*)d_in[1];
    const int*   batch  = (const int*)d_in[2];
    const float* W_f1   = (const float*)d_in[3];
    const float* b_f1   = (const float*)d_in[4];
    const float* W_f2   = (const float*)d_in[5];
    const float* b_f2   = (const float*)d_in[6];
    const float* W_l0   = (const float*)d_in[7];
    const float* b_l0   = (const float*)d_in[8];
    const float* G1     = (const float*)d_in[9];
    const float* b_g1   = (const float*)d_in[10];
    const float* L1     = (const float*)d_in[11];
    const float* G2     = (const float*)d_in[12];
    const float* b_g2   = (const float*)d_in[13];
    const float* L2     = (const float*)d_in[14];
    const float* gam    = (const float*)d_in[15];
    const float* bet    = (const float*)d_in[16];
    const float* W_att  = (const float*)d_in[17];
    const float* b_att  = (const float*)d_in[18];
    const float* A_att  = (const float*)d_in[19];

    const int N = in_sizes[2];
    const int E = in_sizes[1] / 2;
    const int Npad = (N + 127) & ~127;

    char* p = (char*)d_ws;
    auto alloc = [&](size_t bytes) {
        char* r = p;
        p += (bytes + 255) & ~(size_t)255;
        return r;
    };

    short* x_bf   = (short*)alloc((size_t)Npad * 128 * 2);
    short* q_bf   = (short*)alloc((size_t)Npad * 128 * 2);
    short* hid_bf = (short*)alloc((size_t)Npad * 256 * 2);
    short* s0_bf  = (short*)alloc((size_t)Npad * 64 * 2);
    short* s1_bf  = (short*)alloc((size_t)Npad * 64 * 2);
    short* x0_bf  = (short*)alloc((size_t)Npad * 128 * 2);
    float* a_arr  = (float*)alloc((size_t)N * 4);
    float* b_arr  = (float*)alloc((size_t)N * 4);
    float* Tbuf   = (float*)alloc((size_t)HEADS * 128 * 128 * 4);
    short* Mt     = (short*)alloc(128 * 128 * 2);
    float* u_v    = (float*)alloc(128 * 4);
    float* v_v    = (float*)alloc(128 * 4);
    float* c0_v   = (float*)alloc(4);
    short* Wf1t   = (short*)alloc(256 * 128 * 2);
    short* Wefft  = (short*)alloc(64 * 256 * 2);
    float* beff   = (float*)alloc(64 * 4);
    short* G1t    = (short*)alloc(64 * 64 * 2);
    short* G2t    = (short*)alloc(128 * 64 * 2);
    float* zblk   = (float*)alloc((64 * 64 * 2 + 64 + 256) * 4);
    float* xm1    = (float*)alloc(64 * 64 * 4);
    float* xm2    = (float*)alloc(64 * 128 * 4);
    float* bscale = (float*)alloc(128 * 4);
    float* bshift = (float*)alloc(128 * 4);

    if ((size_t)(p - (char*)d_ws) > ws_size) return;

    float* sums1   = zblk;
    float* sums2   = zblk + 64 * 64;
    float* cnt     = zblk + 64 * 64 * 2;
    float* bnsum   = cnt + 64;
    float* bnsumsq = bnsum + 128;

    float* out0    = (float*)d_out;
    float* att_out = out0 + (size_t)N * 128;

    hipMemsetAsync(zblk, 0, (64 * 64 * 2 + 64 + 256) * 4, stream);

    // prologue: pack x, fold attention weights, transpose weights
    {
        long n_in_e = (long)N * 128, n_out_e = (long)Npad * 128;
        long blocks = (n_out_e / 4 + 255) / 256;
        f32_to_bf16_pad<<<(int)blocks, 256, 0, stream>>>(x, x_bf, n_in_e, n_out_e);
    }
    att_fold1<<<dim3(128, HEADS), 128, 0, stream>>>(A_att, W_att, Tbuf);
    att_fold2<<<128, 128, 0, stream>>>(W_att, Tbuf, Mt);
    att_fold3<<<1, 128, 0, stream>>>(W_att, b_att, A_att, u_v, v_v, c0_v);
    node_ab<<<(N * 16 + 255) / 256, 256, 0, stream>>>(x, u_v, v_v, a_arr, b_arr, N);
    wf1_transpose<<<128, 256, 0, stream>>>(W_f1, Wf1t);
    build_weff<<<257, 64, 0, stream>>>(W_f2, b_f2, W_l0, b_l0, Wefft, beff);
    transpose_g<<<192, 64, 0, stream>>>(G1, G2, G1t, G2t);

    const int gmm = Npad / 128;

    // q = x @ M  (N x 128, bf16)
    gemm_mfma<128><<<dim3(gmm, 1), 256, 0, stream>>>(
        x_bf, Mt, nullptr, nullptr, nullptr, q_bf, nullptr, nullptr,
        N, 128, 128, 0);
    // att = sigmoid(0.25*(q[r].x[c] + a[r] + b[c] + c0))
    edge_att<<<(E * 16 + 255) / 256, 256, 0, stream>>>(
        q_bf, x_bf, ei, ei + E, a_arr, b_arr, c0_v, att_out, E);

    // hidden = relu(x @ W_f1 + b_f1)  (N x 256, bf16)
    gemm_mfma<128><<<dim3(gmm, 2), 256, 0, stream>>>(
        x_bf, Wf1t, b_f1, nullptr, nullptr, hid_bf, nullptr, nullptr,
        N, 128, 256, 1);
    // s0 = relu(hidden @ W_eff + b_eff)  (N x 64, bf16)
    gemm_mfma<64><<<dim3(gmm, 1), 256, 0, stream>>>(
        hid_bf, Wefft, beff, nullptr, nullptr, s0_bf, nullptr, nullptr,
        N, 256, 64, 1);

    segmean_bf<<<(N + 255) / 256, 256, 0, stream>>>(s0_bf, batch, sums1, cnt, N, 1);
    xm_compute<<<64, 64, 0, stream>>>(sums1, cnt, L1, xm1, 64);
    // s1 = relu(s0 @ G1 + b_g1 - xm1[batch])  (N x 64, bf16)
    gemm_mfma<64><<<dim3(gmm, 1), 256, 0, stream>>>(
        s0_bf, G1t, b_g1, xm1, batch, s1_bf, nullptr, nullptr,
        N, 64, 64, 1);
    segmean_bf<<<(N + 255) / 256, 256, 0, stream>>>(s1_bf, batch, sums2, cnt, N, 0);
    xm_compute<<<64, 128, 0, stream>>>(sums2, cnt, L2, xm2, 128);
    // x0 = s1 @ G2 + b_g2 - xm2[batch]  (N x 128, bf16) + fused BN stats
    gemm_mfma<128><<<dim3(gmm, 1), 256, 0, stream>>>(
        s1_bf, G2t, b_g2, xm2, batch, x0_bf, bnsum, bnsumsq,
        N, 64, 128, 0);

    bn_final<<<1, 128, 0, stream>>>(bnsum, bnsumsq, gam, bet, bscale, bshift, 1.f / (float)N);
    finalize<<<((N * 128 / 4) + 255) / 256, 256, 0, stream>>>(x, x0_bf, bscale, bshift,
                                                              out0, N * 128 / 4);
}